// Round 3
// baseline (574.991 us; speedup 1.0000x reference)
//
#include <hip/hip_runtime.h>

// Fused single-head causal attention: B=2048, T=128, C=384, HS=64.
// Input/output dtypes detected at runtime (bf16 vs f32 per tensor) because the
// dataset's dtypes are ambiguous: a tiny detector kernel inspects the bit
// patterns and publishes flags in d_ws; compute is always bf16 MFMA.
// One block = one batch element; 256 threads = 4 waves.
// Phase 1: Q,K,V = X @ W{q,k,v}  (A = X from global, B = Wt staged in LDS)
// Phase 2: S^T = K Q^T -> in-register causal softmax -> P to LDS -> O^T = Vt P^T.

typedef __attribute__((ext_vector_type(8))) short bf16x8;
typedef __attribute__((ext_vector_type(4))) float f32x4;

#define MFMA(a, b, c) __builtin_amdgcn_mfma_f32_16x16x32_bf16((a), (b), (c), 0, 0, 0)

__device__ __forceinline__ unsigned short f2bf(float f) {
  union { float f; unsigned int u; } x; x.f = f;
  unsigned int u = x.u;
  unsigned int r = (u + 0x7fffu + ((u >> 16) & 1u)) >> 16;  // RNE
  return (unsigned short)r;
}

__device__ __forceinline__ unsigned int pk2(float a, float b) {
  return (unsigned int)f2bf(a) | ((unsigned int)f2bf(b) << 16);
}

union U8 { bf16x8 v; unsigned int u[4]; };

// ---- dtype detector: for f32 data, even 16-bit words are mantissa noise with
// uniform-random "bf16 exponent" fields; for real bf16 N(0,1)/U(+-.05) data the
// exponent field never reaches 0xC0. flags[i] = 1 -> tensor i is float32.
__global__ void detect_dtype(const unsigned short* __restrict__ X,
                             const unsigned short* __restrict__ Wq,
                             int* __restrict__ flags)
{
  const unsigned short* p = blockIdx.x ? Wq : X;
  int insane = 0;
  #pragma unroll
  for (int i = 0; i < 16; ++i) {
    unsigned short w = p[(threadIdx.x * 16 + i) * 2];  // even words only
    int e = (w >> 7) & 0xFF;
    insane += (e >= 0xC0);
  }
  #pragma unroll
  for (int off = 32; off; off >>= 1) insane += __shfl_down(insane, off, 64);
  if (threadIdx.x == 0) flags[blockIdx.x] = (insane > 8) ? 1 : 0;
}

// ---- Pre-transpose: W[c][h] (384x64) -> Wt[m][h][c] (64x384) as bf16.
__global__ void wt_transpose(const void* __restrict__ Wq,
                             const void* __restrict__ Wk,
                             const void* __restrict__ Wv,
                             const int* __restrict__ flags,
                             unsigned short* __restrict__ Wt)
{
  const int wf = flags[1];
  const int m = blockIdx.x >> 6;
  const int h = blockIdx.x & 63;
  const void* W = (m == 0) ? Wq : (m == 1) ? Wk : Wv;
  unsigned short* o = Wt + (size_t)(m * 64 + h) * 384;
  if (wf) {
    const float* Wf = (const float*)W;
    #pragma unroll
    for (int j = 0; j < 3; ++j) {
      const int c = j * 128 + threadIdx.x;
      o[c] = f2bf(Wf[c * 64 + h]);
    }
  } else {
    const unsigned short* Wu = (const unsigned short*)W;
    #pragma unroll
    for (int j = 0; j < 3; ++j) {
      const int c = j * 128 + threadIdx.x;
      o[c] = Wu[c * 64 + h];
    }
  }
}

// LDS layout (ushort element offsets), total 27136 ushorts = 54272 B:
//   sQ  [    0,  9216)  Q[t][hs],  stride 72 (144 B rows: 16B-aligned)
//   sK  [ 9216, 18432)  K[t][hs],  stride 72
//   sVt [18432, 27136)  Vt[hs][t], stride 136 (written after sW is dead)
//   sW  [18432, 26112)  W stage [3][64][40]  (phase-1 loop only; aliases sVt)
//   sP  [    0, 17408)  P[tq][tk], stride 136 (aliases sQ+sK after phase 2a)
#define SQ  0
#define SK  9216
#define SVT 18432
#define SW  18432
#define SP  0

__global__ __launch_bounds__(256, 2)
void attn_kernel(const void* __restrict__ Xv,
                 const unsigned short* __restrict__ Wt,
                 const int* __restrict__ flags,
                 void* __restrict__ Outv)
{
  __shared__ unsigned short smem[27136];

  const int xf  = flags[0];            // x is float32
  const int wf  = flags[1];            // weights are float32
  const int obf = (xf == 0) & (wf == 0);  // jnp promotion: out bf16 iff all-bf16

  const int tid  = threadIdx.x;
  const int wave = tid >> 6;
  const int lane = tid & 63;
  const int g    = lane >> 4;   // quad 0..3
  const int l16  = lane & 15;
  const int b    = blockIdx.x;
  const int wr   = wave * 32;   // wave's t-row base

  // ---------------- Phase 1: Q,K,V = X @ W ----------------
  f32x4 qacc[2][4], kacc[2][4], vacc[2][4];
  #pragma unroll
  for (int i = 0; i < 2; ++i)
    #pragma unroll
    for (int j = 0; j < 4; ++j) {
      qacc[i][j] = f32x4{0.f, 0.f, 0.f, 0.f};
      kacc[i][j] = f32x4{0.f, 0.f, 0.f, 0.f};
      vacc[i][j] = f32x4{0.f, 0.f, 0.f, 0.f};
    }

  // W staging: thread -> (h = tid>>2, quad = tid&3)
  const int sh  = tid >> 2;
  const int sq4 = tid & 3;
  const unsigned short* wg = Wt + sh * 384 + sq4 * 8;
  const int sws  = SW + sh * 40 + sq4 * 8;
  const int swr_ = SW + l16 * 40 + g * 8;

  uint4 w0 = *(const uint4*)(wg);
  uint4 w1 = *(const uint4*)(wg + 24576);
  uint4 w2 = *(const uint4*)(wg + 49152);

  if (xf) {  // ---- X is float32: two float4 loads + convert per A-frag ----
    const float* xa0 = (const float*)Xv + (size_t)b * 49152 + (size_t)(wr + l16) * 384 + g * 8;
    const float* xa1 = xa0 + 16 * 384;
    #pragma unroll 1
    for (int kc = 0; kc < 12; ++kc) {
      __syncthreads();
      *(uint4*)&smem[sws       ] = w0;
      *(uint4*)&smem[sws + 2560] = w1;
      *(uint4*)&smem[sws + 5120] = w2;
      __syncthreads();
      const int k0 = kc * 32;
      float4 p0 = *(const float4*)(xa0 + k0);
      float4 p1 = *(const float4*)(xa0 + k0 + 4);
      float4 p2 = *(const float4*)(xa1 + k0);
      float4 p3 = *(const float4*)(xa1 + k0 + 4);
      if (kc < 11) {
        w0 = *(const uint4*)(wg + k0 + 32);
        w1 = *(const uint4*)(wg + 24576 + k0 + 32);
        w2 = *(const uint4*)(wg + 49152 + k0 + 32);
      }
      U8 a0, a1;
      a0.u[0] = pk2(p0.x, p0.y); a0.u[1] = pk2(p0.z, p0.w);
      a0.u[2] = pk2(p1.x, p1.y); a0.u[3] = pk2(p1.z, p1.w);
      a1.u[0] = pk2(p2.x, p2.y); a1.u[1] = pk2(p2.z, p2.w);
      a1.u[2] = pk2(p3.x, p3.y); a1.u[3] = pk2(p3.z, p3.w);
      #pragma unroll
      for (int nt = 0; nt < 4; ++nt) {
        bf16x8 bq = *(const bf16x8*)&smem[swr_ + nt * 640];
        bf16x8 bk = *(const bf16x8*)&smem[swr_ + 2560 + nt * 640];
        bf16x8 bv = *(const bf16x8*)&smem[swr_ + 5120 + nt * 640];
        qacc[0][nt] = MFMA(a0.v, bq, qacc[0][nt]);
        qacc[1][nt] = MFMA(a1.v, bq, qacc[1][nt]);
        kacc[0][nt] = MFMA(a0.v, bk, kacc[0][nt]);
        kacc[1][nt] = MFMA(a1.v, bk, kacc[1][nt]);
        vacc[0][nt] = MFMA(a0.v, bv, vacc[0][nt]);
        vacc[1][nt] = MFMA(a1.v, bv, vacc[1][nt]);
      }
    }
  } else {  // ---- X is bf16: one bf16x8 load per A-frag ----
    const unsigned short* xa0 = (const unsigned short*)Xv + (size_t)b * 49152 + (size_t)(wr + l16) * 384 + g * 8;
    const unsigned short* xa1 = xa0 + 16 * 384;
    #pragma unroll 1
    for (int kc = 0; kc < 12; ++kc) {
      __syncthreads();
      *(uint4*)&smem[sws       ] = w0;
      *(uint4*)&smem[sws + 2560] = w1;
      *(uint4*)&smem[sws + 5120] = w2;
      __syncthreads();
      const int k0 = kc * 32;
      bf16x8 a0 = *(const bf16x8*)(xa0 + k0);
      bf16x8 a1 = *(const bf16x8*)(xa1 + k0);
      if (kc < 11) {
        w0 = *(const uint4*)(wg + k0 + 32);
        w1 = *(const uint4*)(wg + 24576 + k0 + 32);
        w2 = *(const uint4*)(wg + 49152 + k0 + 32);
      }
      #pragma unroll
      for (int nt = 0; nt < 4; ++nt) {
        bf16x8 bq = *(const bf16x8*)&smem[swr_ + nt * 640];
        bf16x8 bk = *(const bf16x8*)&smem[swr_ + 2560 + nt * 640];
        bf16x8 bv = *(const bf16x8*)&smem[swr_ + 5120 + nt * 640];
        qacc[0][nt] = MFMA(a0, bq, qacc[0][nt]);
        qacc[1][nt] = MFMA(a1, bq, qacc[1][nt]);
        kacc[0][nt] = MFMA(a0, bk, kacc[0][nt]);
        kacc[1][nt] = MFMA(a1, bk, kacc[1][nt]);
        vacc[0][nt] = MFMA(a0, bv, vacc[0][nt]);
        vacc[1][nt] = MFMA(a1, bv, vacc[1][nt]);
      }
    }
  }
  __syncthreads();   // sW dead for ALL waves (sVt aliases it)

  // Epilogue: lane holds D[row = g*4+r][col = l16] per 16x16 tile.
  #pragma unroll
  for (int mt = 0; mt < 2; ++mt) {
    #pragma unroll
    for (int nt = 0; nt < 4; ++nt) {
      const int hs = nt * 16 + l16;
      #pragma unroll
      for (int r = 0; r < 4; ++r) {
        const int t = wr + mt * 16 + g * 4 + r;
        smem[SQ  + t * 72   + hs] = f2bf(qacc[mt][nt][r]);
        smem[SK  + t * 72   + hs] = f2bf(kacc[mt][nt][r]);
        smem[SVT + hs * 136 + t ] = f2bf(vacc[mt][nt][r]);
      }
    }
  }
  __syncthreads();

  // ---------------- Phase 2a: S^T = K @ Q^T ----------------
  // sacc[mt][nt]: S^T[t_k = mt*16 + g*4 + r][t_q = wr + nt*16 + l16]
  f32x4 sacc[8][2];
  #pragma unroll
  for (int mt = 0; mt < 8; ++mt) {
    sacc[mt][0] = f32x4{0.f, 0.f, 0.f, 0.f};
    sacc[mt][1] = f32x4{0.f, 0.f, 0.f, 0.f};
  }
  #pragma unroll
  for (int kc = 0; kc < 2; ++kc) {
    const int u = kc * 4 + g;
    bf16x8 bq[2];
    #pragma unroll
    for (int nt = 0; nt < 2; ++nt) {
      const int tq = wr + nt * 16 + l16;
      bq[nt] = *(const bf16x8*)&smem[SQ + tq * 72 + u * 8];
    }
    #pragma unroll
    for (int mt = 0; mt < 8; ++mt) {
      const int tk = mt * 16 + l16;
      bf16x8 ak = *(const bf16x8*)&smem[SK + tk * 72 + u * 8];
      sacc[mt][0] = MFMA(ak, bq[0], sacc[mt][0]);
      sacc[mt][1] = MFMA(ak, bq[1], sacc[mt][1]);
    }
  }

  // ---------------- Softmax (in-register, over t_k) ----------------
  const float scale = 0.051031036307982884f;  // 384^-0.5
  #pragma unroll
  for (int nt = 0; nt < 2; ++nt) {
    const int tq = wr + nt * 16 + l16;
    float mx = -1e30f;
    #pragma unroll
    for (int mt = 0; mt < 8; ++mt)
      #pragma unroll
      for (int r = 0; r < 4; ++r) {
        const int tk = mt * 16 + g * 4 + r;
        float s = sacc[mt][nt][r] * scale;
        s = (tk <= tq) ? s : -1e30f;              // finite causal mask
        sacc[mt][nt][r] = s;
        mx = fmaxf(mx, s);
      }
    mx = fmaxf(mx, __shfl_xor(mx, 16, 64));
    mx = fmaxf(mx, __shfl_xor(mx, 32, 64));
    float sum = 0.f;
    #pragma unroll
    for (int mt = 0; mt < 8; ++mt)
      #pragma unroll
      for (int r = 0; r < 4; ++r) {
        float p = exp2f((sacc[mt][nt][r] - mx) * 1.4426950408889634f);
        sacc[mt][nt][r] = p;
        sum += p;
      }
    sum += __shfl_xor(sum, 16, 64);
    sum += __shfl_xor(sum, 32, 64);
    const float inv = 1.f / sum;
    #pragma unroll
    for (int mt = 0; mt < 8; ++mt)
      #pragma unroll
      for (int r = 0; r < 4; ++r)
        sacc[mt][nt][r] *= inv;
  }

  __syncthreads();   // all waves done reading sQ/sK; safe to overwrite with P
  #pragma unroll
  for (int nt = 0; nt < 2; ++nt) {
    const int tq = wr + nt * 16 + l16;
    #pragma unroll
    for (int mt = 0; mt < 8; ++mt)
      #pragma unroll
      for (int r = 0; r < 4; ++r) {
        const int tk = mt * 16 + g * 4 + r;
        smem[SP + tq * 136 + tk] = f2bf(sacc[mt][nt][r]);
      }
  }
  __syncthreads();

  // ---------------- Phase 2c: O^T = Vt @ P^T ----------------
  f32x4 oacc[4][2];
  #pragma unroll
  for (int mt = 0; mt < 4; ++mt) {
    oacc[mt][0] = f32x4{0.f, 0.f, 0.f, 0.f};
    oacc[mt][1] = f32x4{0.f, 0.f, 0.f, 0.f};
  }
  #pragma unroll
  for (int kc = 0; kc < 4; ++kc) {
    const int u = kc * 4 + g;
    bf16x8 bp[2];
    #pragma unroll
    for (int nt = 0; nt < 2; ++nt) {
      const int tq = wr + nt * 16 + l16;
      bp[nt] = *(const bf16x8*)&smem[SP + tq * 136 + u * 8];
    }
    #pragma unroll
    for (int mt = 0; mt < 4; ++mt) {
      const int hs = mt * 16 + l16;
      bf16x8 av = *(const bf16x8*)&smem[SVT + hs * 136 + u * 8];
      oacc[mt][0] = MFMA(av, bp[0], oacc[mt][0]);
      oacc[mt][1] = MFMA(av, bp[1], oacc[mt][1]);
    }
  }

  // oacc[mt][nt][r] = O[tq = wr+nt*16+l16][hs = mt*16 + g*4 + r]
  if (obf) {
    unsigned short* ob = (unsigned short*)Outv + (size_t)b * 8192;
    #pragma unroll
    for (int nt = 0; nt < 2; ++nt) {
      const int tq = wr + nt * 16 + l16;
      #pragma unroll
      for (int mt = 0; mt < 4; ++mt) {
        const int hs0 = mt * 16 + g * 4;
        uint2 oo;
        oo.x = pk2(oacc[mt][nt][0], oacc[mt][nt][1]);
        oo.y = pk2(oacc[mt][nt][2], oacc[mt][nt][3]);
        *(uint2*)(ob + tq * 64 + hs0) = oo;
      }
    }
  } else {
    float* of = (float*)Outv + (size_t)b * 8192;
    #pragma unroll
    for (int nt = 0; nt < 2; ++nt) {
      const int tq = wr + nt * 16 + l16;
      #pragma unroll
      for (int mt = 0; mt < 4; ++mt) {
        const int hs0 = mt * 16 + g * 4;
        float4 oo;
        oo.x = oacc[mt][nt][0]; oo.y = oacc[mt][nt][1];
        oo.z = oacc[mt][nt][2]; oo.w = oacc[mt][nt][3];
        *(float4*)(of + tq * 64 + hs0) = oo;
      }
    }
  }
}

extern "C" void kernel_launch(void* const* d_in, const int* in_sizes, int n_in,
                              void* d_out, int out_size, void* d_ws, size_t ws_size,
                              hipStream_t stream)
{
  const void* X  = d_in[0];
  const void* Wq = d_in[1];
  const void* Wk = d_in[2];
  const void* Wv = d_in[3];
  int* flags = (int*)d_ws;                                   // [0]=x_f32 [1]=w_f32
  unsigned short* Wt = (unsigned short*)((char*)d_ws + 256); // 147456 B bf16
  const int B = in_sizes[0] / 49152;                         // 2048

  hipLaunchKernelGGL(detect_dtype, dim3(2), dim3(64), 0, stream,
                     (const unsigned short*)X, (const unsigned short*)Wq, flags);
  hipLaunchKernelGGL(wt_transpose, dim3(192), dim3(128), 0, stream, Wq, Wk, Wv, flags, Wt);
  hipLaunchKernelGGL(attn_kernel, dim3(B), dim3(256), 0, stream, X, Wt, flags, d_out);
}